// Round 10
// baseline (304.327 us; speedup 1.0000x reference)
//
#include <hip/hip_runtime.h>
#include <hip/hip_bf16.h>
#include <math.h>

#define NTOK 16384
#define DDIM 1024
#define HALF 512
#define SUB  512
#define KDIM 512
#define TOPK 8
#define NCAND 16
#define VDIM 128
#define TMB 32          // tokens per block (score kernel)

typedef __attribute__((ext_vector_type(8))) _Float16 f16x8;
typedef __attribute__((ext_vector_type(4))) float f32x4;

static __device__ __forceinline__ int pk2(float a, float b) {
    _Float16 ha = (_Float16)a, hb = (_Float16)b;
    return (int)__builtin_bit_cast(unsigned short, ha)
         | ((int)__builtin_bit_cast(unsigned short, hb) << 16);
}
static __device__ __forceinline__ void splitpk(float a, float b, int& h, int& l) {
    _Float16 ha = (_Float16)a, hb = (_Float16)b;
    _Float16 la = (_Float16)(a - (float)ha), lb = (_Float16)(b - (float)hb);
    h = (int)__builtin_bit_cast(unsigned short, ha)
      | ((int)__builtin_bit_cast(unsigned short, hb) << 16);
    l = (int)__builtin_bit_cast(unsigned short, la)
      | ((int)__builtin_bit_cast(unsigned short, lb) << 16);
}

// ---------------------------------------------------------------------------
// Kernel 0: codebooks -> single-f16 MFMA-B fragments.
//   slice = hf*4 + cq (cq = 128-cand wave slice); step s = kstep*8 + nt.
//   frag elem: n = cq*128 + nt*16 + (lane&15), k = kstep*32 + (lane>>4)*8 + j.
// ---------------------------------------------------------------------------
__global__ __launch_bounds__(256)
void cvt_bfrag(const float* __restrict__ cb1, const float* __restrict__ cb2,
               char* __restrict__ Bp)
{
    int fid   = blockIdx.x * 256 + threadIdx.x;   // 0..65535
    int lane  = fid & 63;
    int s     = (fid >> 6) & 127;
    int slice = fid >> 13;
    int nt = s & 7, kstep = s >> 3;
    int cq = slice & 3, hf = slice >> 2;
    const float* cb = hf ? cb2 : cb1;
    int n = cq * 128 + nt * 16 + (lane & 15);
    int k = kstep * 32 + (lane >> 4) * 8;
    const float* src = cb + (size_t)n * KDIM + k;
    float4 f0 = *(const float4*)src;
    float4 f1 = *(const float4*)(src + 4);
    int4 v;
    v.x = pk2(f0.x, f0.y); v.y = pk2(f0.z, f0.w);
    v.z = pk2(f1.x, f1.y); v.w = pk2(f1.z, f1.w);
    *(int4*)(Bp + (size_t)fid * 16) = v;
}

// ---------------------------------------------------------------------------
// Phase 2 for one 16-token round. acc passed as array-REFERENCE so every
// index is compile-time static (rule #20: no runtime-indexed reg arrays).
// ---------------------------------------------------------------------------
static __device__ __forceinline__ void phase2_round(
    const f32x4 (&acc)[8], const int rr,
    float* __restrict__ sS, const int tok0, const int hf,
    const int lane, const int wid, const int l15, const int lh,
    const float* __restrict__ query, const float* __restrict__ cbf,
    int* __restrict__ tk_idx, float* __restrict__ tk_val)
{
    const int qoff = hf * HALF;

    // dump: C/D layout row=(lane>>4)*4+r (token), col=lane&15 (cand)
    #pragma unroll
    for (int nt = 0; nt < 8; nt++)
        #pragma unroll
        for (int r = 0; r < 4; r++) {
            int t = lh * 4 + r;                       // 0..15
            int c = wid * 128 + nt * 16 + l15;
            sS[t * SUB + (c ^ (lh << 3))] = acc[nt][r];
        }
    __syncthreads();

    for (int v = 0; v < 4; v++) {
        const int t   = wid * 4 + v;                  // 0..15
        const int tok = tok0 + rr * 16 + t;
        const int hsh = ((t >> 2) & 3) << 3;

        float sv[8];
        #pragma unroll
        for (int j = 0; j < 8; j++) sv[j] = sS[t * SUB + ((lane + 64 * j) ^ hsh)];

        float m = sv[0];
        #pragma unroll
        for (int j = 1; j < 8; j++) m = fmaxf(m, sv[j]);
        #pragma unroll
        for (int off = 32; off > 0; off >>= 1) m = fmaxf(m, __shfl_xor(m, off));

        auto wave_cnt = [&](float tau) -> int {
            int c = 0;
            #pragma unroll
            for (int j = 0; j < 8; j++)
                c += __popcll(__ballot(sv[j] > tau));
            return c;
        };

        float lo = m - 0.5f, hi = m;
        while (wave_cnt(lo) < 9) lo -= 0.5f;
        for (int it = 0; it < 14; it++) {
            float mid = 0.5f * (lo + hi);
            if (wave_cnt(mid) >= 9) lo = mid; else hi = mid;
        }
        int ch8 = wave_cnt(hi);

        float v8 = 1e30f, v9 = -1e30f;
        #pragma unroll
        for (int j = 0; j < 8; j++) {
            bool sel = sv[j] > hi;
            v8 = sel ? fminf(v8, sv[j]) : v8;
            v9 = sel ? v9 : fmaxf(v9, sv[j]);
        }
        #pragma unroll
        for (int off = 32; off > 0; off >>= 1) {
            v8 = fminf(v8, __shfl_xor(v8, off));
            v9 = fmaxf(v9, __shfl_xor(v9, off));
        }

        if (ch8 == 8 && (v8 - v9) > 1e-3f) {
            // fast path: coarse top-8 set exact at ~8-sigma margin (R9-proven)
            int base = 0;
            #pragma unroll
            for (int j = 0; j < 8; j++) {
                unsigned long long mk = __ballot(sv[j] > hi);
                if (sv[j] > hi) {
                    int pos = base + __popcll(mk & ((1ULL << lane) - 1ULL));
                    tk_idx[((size_t)tok * 2 + hf) * TOPK + pos] = lane + 64 * j;
                    tk_val[((size_t)tok * 2 + hf) * TOPK + pos] = sv[j];
                }
                base += __popcll(mk);
            }
        } else {
            // slow path (~4%): coarse top-16 + fp64 rescore, exact ordering
            int cand[NCAND];
            #pragma unroll
            for (int r = 0; r < NCAND; r++) {
                float bv = sv[0]; int bj = 0;
                #pragma unroll
                for (int j = 1; j < 8; j++) if (sv[j] > bv) { bv = sv[j]; bj = j; }
                int bidx = lane + 64 * bj;
                #pragma unroll
                for (int off = 32; off > 0; off >>= 1) {
                    float ov = __shfl_xor(bv, off);
                    int   oi = __shfl_xor(bidx, off);
                    if (ov > bv || (ov == bv && oi < bidx)) { bv = ov; bidx = oi; }
                }
                cand[r] = bidx;
                int jj = bidx >> 6;
                if ((bidx & 63) == lane) {
                    #pragma unroll
                    for (int j = 0; j < 8; j++) if (j == jj) sv[j] = -INFINITY;
                }
            }
            double qd[8];
            #pragma unroll
            for (int j = 0; j < 8; j++)
                qd[j] = (double)query[(size_t)tok * DDIM + qoff + lane + 64 * j];
            double rv[NCAND];
            #pragma unroll
            for (int r = 0; r < NCAND; r++) {
                const float* __restrict__ crow = &cbf[(size_t)cand[r] * KDIM];
                double a = 0.0;
                #pragma unroll
                for (int j = 0; j < 8; j++)
                    a = fma(qd[j], (double)crow[lane + 64 * j], a);
                #pragma unroll
                for (int off = 32; off > 0; off >>= 1)
                    a += __shfl_xor(a, off);
                rv[r] = a;
            }
            if (lane == 0) {
                #pragma unroll
                for (int r = 0; r < NCAND; r++) {
                    int rk = 0;
                    #pragma unroll
                    for (int mm = 0; mm < NCAND; mm++)
                        if (rv[mm] > rv[r] || (rv[mm] == rv[r] && cand[mm] < cand[r])) rk++;
                    if (rk < TOPK) {
                        tk_idx[((size_t)tok * 2 + hf) * TOPK + rk] = cand[r];
                        tk_val[((size_t)tok * 2 + hf) * TOPK + rk] = (float)rv[r];
                    }
                }
            }
        }
    }
    __syncthreads();
}

// ---------------------------------------------------------------------------
// Kernel 1: fused score+topk. 256 threads (4 waves), 32 tokens, one half.
//   Wave = 128 cands (8 nt). f16 2-term: s = qh*c + ql*c.
//   A staged in two K-halves (32 KB LDS) as ready-to-read fragments.
//   B streamed global->reg via 4-slot ring (consume s, reload s+4).
// ---------------------------------------------------------------------------
__global__ __launch_bounds__(256, 4)
void score_topk_fused(const float* __restrict__ query,
                      const float* __restrict__ cb1f,
                      const float* __restrict__ cb2f,
                      const char* __restrict__ Bp,
                      int*   __restrict__ tk_idx,
                      float* __restrict__ tk_val)
{
    __shared__ char smem[32768];
    // GEMM: A frags [seg(8)][tt(2)][hi/lo][lane*16B]; phase 2: sS[16][512]
    float* sS = (float*)smem;

    const int tid  = threadIdx.x;
    const int hf   = blockIdx.y;
    const int tok0 = blockIdx.x * TMB;
    const float* __restrict__ cbf = hf ? cb2f : cb1f;
    const int qoff = hf * HALF;

    const int lane = tid & 63;
    const int wid  = tid >> 6;          // 0..3 = 128-cand slice
    const int l15  = lane & 15;
    const int lh   = lane >> 4;

    const char* bp = Bp + (size_t)(hf * 4 + wid) * 131072 + lane * 16;
    int4 ring[4];
    #pragma unroll
    for (int j = 0; j < 4; j++) ring[j] = *(const int4*)(bp + j * 1024);

    f32x4 acc0[8], acc1[8];
    #pragma unroll
    for (int nt = 0; nt < 8; nt++) {
        acc0[nt] = (f32x4){0.f, 0.f, 0.f, 0.f};
        acc1[nt] = (f32x4){0.f, 0.f, 0.f, 0.f};
    }

    for (int h = 0; h < 2; h++) {
        // ---- stage A half h: 32 tok x 256 k -> qh/ql f16 fragments ----
        {
            const int tok = tid >> 3;       // 0..31
            const int seg = tid & 7;        // local kstep
            const int tt  = tok >> 4;
            const int row = tok & 15;
            const float* src = query + (size_t)(tok0 + tok) * DDIM + qoff
                               + h * 256 + seg * 32;
            char* base = smem + seg * 4096 + tt * 2048;
            #pragma unroll
            for (int j8 = 0; j8 < 4; j8++) {
                float4 f0 = *(const float4*)(src + j8 * 8);
                float4 f1 = *(const float4*)(src + j8 * 8 + 4);
                int4 vh, vl;
                splitpk(f0.x, f0.y, vh.x, vl.x);
                splitpk(f0.z, f0.w, vh.y, vl.y);
                splitpk(f1.x, f1.y, vh.z, vl.z);
                splitpk(f1.z, f1.w, vh.w, vl.w);
                const int lw = j8 * 16 + row;
                *(int4*)(base + lw * 16)        = vh;
                *(int4*)(base + 1024 + lw * 16) = vl;
            }
        }
        __syncthreads();

        for (int ks = 0; ks < 8; ks++) {
            const char* abase = smem + ks * 4096;
            f16x8 qh0 = *(const f16x8*)(abase + lane * 16);
            f16x8 ql0 = *(const f16x8*)(abase + 1024 + lane * 16);
            f16x8 qh1 = *(const f16x8*)(abase + 2048 + lane * 16);
            f16x8 ql1 = *(const f16x8*)(abase + 3072 + lane * 16);
            const int sbase = (h * 8 + ks) * 8;
            #pragma unroll
            for (int nt = 0; nt < 8; nt++) {
                f16x8 b = __builtin_bit_cast(f16x8, ring[nt & 3]);
                ring[nt & 3] = *(const int4*)(bp + ((sbase + nt + 4) & 127) * 1024);
                acc0[nt] = __builtin_amdgcn_mfma_f32_16x16x32_f16(qh0, b, acc0[nt], 0, 0, 0);
                acc1[nt] = __builtin_amdgcn_mfma_f32_16x16x32_f16(qh1, b, acc1[nt], 0, 0, 0);
                acc0[nt] = __builtin_amdgcn_mfma_f32_16x16x32_f16(ql0, b, acc0[nt], 0, 0, 0);
                acc1[nt] = __builtin_amdgcn_mfma_f32_16x16x32_f16(ql1, b, acc1[nt], 0, 0, 0);
            }
        }
        __syncthreads();   // A(h) reads done before restage / sS overlay
    }

    // ---- phase 2: tokens 0-15 from acc0, 16-31 from acc1 ----
    phase2_round(acc0, 0, sS, tok0, hf, lane, wid, l15, lh,
                 query, cbf, tk_idx, tk_val);
    phase2_round(acc1, 1, sS, tok0, hf, lane, wid, l15, lh,
                 query, cbf, tk_idx, tk_val);
}

// ---------------------------------------------------------------------------
// Kernel 2: one wave per token. softmax(8)x2 -> 64 weighted value rows.
// (R6-proven float2 version)
// ---------------------------------------------------------------------------
__global__ __launch_bounds__(256)
void gather_kernel(const float* __restrict__ values,
                   const int*   __restrict__ tk_idx,
                   const float* __restrict__ tk_val,
                   float* __restrict__ out)
{
    const int tid  = threadIdx.x;
    const int lane = tid & 63;
    const int tok  = blockIdx.x * 4 + (tid >> 6);

    const int b1 = (tok * 2 + 0) * TOPK;
    const int b2 = (tok * 2 + 1) * TOPK;

    float v1[8], v2[8]; int i1[8], i2[8];
    #pragma unroll
    for (int j = 0; j < 8; j++) {
        i1[j] = tk_idx[b1 + j]; v1[j] = tk_val[b1 + j];
        i2[j] = tk_idx[b2 + j]; v2[j] = tk_val[b2 + j];
    }

    float m1 = v1[0], m2 = v2[0];
    #pragma unroll
    for (int j = 1; j < 8; j++) { m1 = fmaxf(m1, v1[j]); m2 = fmaxf(m2, v2[j]); }

    float w1[8], w2[8], s1 = 0.f, s2 = 0.f;
    #pragma unroll
    for (int j = 0; j < 8; j++) {
        w1[j] = expf(v1[j] - m1); s1 += w1[j];
        w2[j] = expf(v2[j] - m2); s2 += w2[j];
    }
    const float inv1 = 1.f / s1, inv2 = 1.f / s2;
    #pragma unroll
    for (int j = 0; j < 8; j++) { w1[j] *= inv1; w2[j] *= inv2; }

    float2 accA = make_float2(0.f, 0.f), accB = make_float2(0.f, 0.f);
    #pragma unroll
    for (int i = 0; i < 8; i++) {
        const int rb = i1[i] * SUB;
        const float wi = w1[i];
        #pragma unroll
        for (int j = 0; j < 8; j += 2) {
            const float wa = wi * w2[j];
            const float wb = wi * w2[j + 1];
            const float* __restrict__ ra  = values + (size_t)(rb + i2[j])     * VDIM;
            const float* __restrict__ rbp = values + (size_t)(rb + i2[j + 1]) * VDIM;
            float2 ta = *(const float2*)&ra[lane * 2];
            float2 tb = *(const float2*)&rbp[lane * 2];
            accA.x = fmaf(wa, ta.x, accA.x);
            accA.y = fmaf(wa, ta.y, accA.y);
            accB.x = fmaf(wb, tb.x, accB.x);
            accB.y = fmaf(wb, tb.y, accB.y);
        }
    }
    float2 acc = make_float2(accA.x + accB.x, accA.y + accB.y);
    *(float2*)&out[(size_t)tok * VDIM + lane * 2] = acc;
}

extern "C" void kernel_launch(void* const* d_in, const int* in_sizes, int n_in,
                              void* d_out, int out_size, void* d_ws, size_t ws_size,
                              hipStream_t stream) {
    const float* query  = (const float*)d_in[0];
    const float* cb1    = (const float*)d_in[1];
    const float* cb2    = (const float*)d_in[2];
    const float* values = (const float*)d_in[3];
    float* out = (float*)d_out;

    char* ws = (char*)d_ws;
    int*   tk_idx = (int*)ws;                    // 1 MB
    float* tk_val = (float*)(ws + (1u << 20));   // 1 MB
    char*  Bp     = ws + (2u << 20);             // 1 MB f16 B fragments

    cvt_bfrag<<<256, 256, 0, stream>>>(cb1, cb2, Bp);
    dim3 g1(NTOK / TMB, 2);
    score_topk_fused<<<g1, 256, 0, stream>>>(query, cb1, cb2, Bp, tk_idx, tk_val);
    gather_kernel<<<NTOK / 4, 256, 0, stream>>>(values, tk_idx, tk_val, out);
}

// Round 11
// 262.746 us; speedup vs baseline: 1.1583x; 1.1583x over previous
//
#include <hip/hip_runtime.h>
#include <hip/hip_bf16.h>
#include <math.h>

#define NTOK 16384
#define DDIM 1024
#define HALF 512
#define SUB  512
#define KDIM 512
#define TOPK 8
#define NCAND 16
#define VDIM 128
#define TMB 32          // tokens per block (score kernel)

typedef __attribute__((ext_vector_type(8))) _Float16 f16x8;
typedef __attribute__((ext_vector_type(4))) float f32x4;

static __device__ __forceinline__ int pk2(float a, float b) {
    _Float16 ha = (_Float16)a, hb = (_Float16)b;
    return (int)__builtin_bit_cast(unsigned short, ha)
         | ((int)__builtin_bit_cast(unsigned short, hb) << 16);
}
static __device__ __forceinline__ void splitpk(float a, float b, int& h, int& l) {
    _Float16 ha = (_Float16)a, hb = (_Float16)b;
    _Float16 la = (_Float16)(a - (float)ha), lb = (_Float16)(b - (float)hb);
    h = (int)__builtin_bit_cast(unsigned short, ha)
      | ((int)__builtin_bit_cast(unsigned short, hb) << 16);
    l = (int)__builtin_bit_cast(unsigned short, la)
      | ((int)__builtin_bit_cast(unsigned short, lb) << 16);
}

// ---------------------------------------------------------------------------
// Kernel 0: codebooks -> single-f16 MFMA-B fragments.
//   slice = hf*4 + cq (cq = 128-cand wave slice); step s = kstep*8 + nt.
//   frag elem: n = cq*128 + nt*16 + (lane&15), k = kstep*32 + (lane>>4)*8 + j.
// ---------------------------------------------------------------------------
__global__ __launch_bounds__(256)
void cvt_bfrag(const float* __restrict__ cb1, const float* __restrict__ cb2,
               char* __restrict__ Bp)
{
    int fid   = blockIdx.x * 256 + threadIdx.x;   // 0..65535
    int lane  = fid & 63;
    int s     = (fid >> 6) & 127;
    int slice = fid >> 13;
    int nt = s & 7, kstep = s >> 3;
    int cq = slice & 3, hf = slice >> 2;
    const float* cb = hf ? cb2 : cb1;
    int n = cq * 128 + nt * 16 + (lane & 15);
    int k = kstep * 32 + (lane >> 4) * 8;
    const float* src = cb + (size_t)n * KDIM + k;
    float4 f0 = *(const float4*)src;
    float4 f1 = *(const float4*)(src + 4);
    int4 v;
    v.x = pk2(f0.x, f0.y); v.y = pk2(f0.z, f0.w);
    v.z = pk2(f1.x, f1.y); v.w = pk2(f1.z, f1.w);
    *(int4*)(Bp + (size_t)fid * 16) = v;
}

// ---------------------------------------------------------------------------
// Kernel 1: fused score+topk. 256 threads (4 waves), 32 tokens, one half.
//   Wave = 128 cands (8 nt). f16 2-term: s = qh*c + ql*c.
//   A staged in two K-halves (32 KB LDS) as ready-to-read fragments.
//   B streamed global->reg via 8-slot ring (reload distance = 8 nt-iters).
//   Phase 2: INLINE static dumps of acc0/acc1 (no array refs, no runtime
//   indices -> no scratch; rule #20) + LDS-only topk lambda.
// ---------------------------------------------------------------------------
__global__ __launch_bounds__(256, 3)
void score_topk_fused(const float* __restrict__ query,
                      const float* __restrict__ cb1f,
                      const float* __restrict__ cb2f,
                      const char* __restrict__ Bp,
                      int*   __restrict__ tk_idx,
                      float* __restrict__ tk_val)
{
    __shared__ char smem[32768];
    // GEMM: A frags [seg(8)][tt(2)][hi/lo][lane*16B]; phase 2: sS[16][512]
    float* sS = (float*)smem;

    const int tid  = threadIdx.x;
    const int hf   = blockIdx.y;
    const int tok0 = blockIdx.x * TMB;
    const float* __restrict__ cbf = hf ? cb2f : cb1f;
    const int qoff = hf * HALF;

    const int lane = tid & 63;
    const int wid  = tid >> 6;          // 0..3 = 128-cand slice
    const int l15  = lane & 15;
    const int lh   = lane >> 4;

    const char* bp = Bp + (size_t)(hf * 4 + wid) * 131072 + lane * 16;
    int4 ring[8];
    #pragma unroll
    for (int j = 0; j < 8; j++) ring[j] = *(const int4*)(bp + j * 1024);

    f32x4 acc0[8], acc1[8];
    #pragma unroll
    for (int nt = 0; nt < 8; nt++) {
        acc0[nt] = (f32x4){0.f, 0.f, 0.f, 0.f};
        acc1[nt] = (f32x4){0.f, 0.f, 0.f, 0.f};
    }

    for (int h = 0; h < 2; h++) {
        // ---- stage A half h: 32 tok x 256 k -> qh/ql f16 fragments ----
        {
            const int tok = tid >> 3;       // 0..31
            const int seg = tid & 7;        // local kstep
            const int tt  = tok >> 4;
            const int row = tok & 15;
            const float* src = query + (size_t)(tok0 + tok) * DDIM + qoff
                               + h * 256 + seg * 32;
            char* base = smem + seg * 4096 + tt * 2048;
            #pragma unroll
            for (int j8 = 0; j8 < 4; j8++) {
                float4 f0 = *(const float4*)(src + j8 * 8);
                float4 f1 = *(const float4*)(src + j8 * 8 + 4);
                int4 vh, vl;
                splitpk(f0.x, f0.y, vh.x, vl.x);
                splitpk(f0.z, f0.w, vh.y, vl.y);
                splitpk(f1.x, f1.y, vh.z, vl.z);
                splitpk(f1.z, f1.w, vh.w, vl.w);
                const int lw = j8 * 16 + row;
                *(int4*)(base + lw * 16)        = vh;
                *(int4*)(base + 1024 + lw * 16) = vl;
            }
        }
        __syncthreads();

        for (int ks = 0; ks < 8; ks++) {
            const char* abase = smem + ks * 4096;
            f16x8 qh0 = *(const f16x8*)(abase + lane * 16);
            f16x8 ql0 = *(const f16x8*)(abase + 1024 + lane * 16);
            f16x8 qh1 = *(const f16x8*)(abase + 2048 + lane * 16);
            f16x8 ql1 = *(const f16x8*)(abase + 3072 + lane * 16);
            const int sbase = (h * 8 + ks) * 8;
            #pragma unroll
            for (int nt = 0; nt < 8; nt++) {
                f16x8 b = __builtin_bit_cast(f16x8, ring[nt]);
                ring[nt] = *(const int4*)(bp + ((sbase + nt + 8) & 127) * 1024);
                acc0[nt] = __builtin_amdgcn_mfma_f32_16x16x32_f16(qh0, b, acc0[nt], 0, 0, 0);
                acc1[nt] = __builtin_amdgcn_mfma_f32_16x16x32_f16(qh1, b, acc1[nt], 0, 0, 0);
                acc0[nt] = __builtin_amdgcn_mfma_f32_16x16x32_f16(ql0, b, acc0[nt], 0, 0, 0);
                acc1[nt] = __builtin_amdgcn_mfma_f32_16x16x32_f16(ql1, b, acc1[nt], 0, 0, 0);
            }
        }
        __syncthreads();   // A(h) reads done before restage / sS overlay
    }

    // ---- phase 2: LDS-only topk worker (reads sS; no register arrays in) ---
    auto topk16 = [&](int rr) {
        for (int v = 0; v < 4; v++) {
            const int t   = wid * 4 + v;                  // 0..15
            const int tok = tok0 + rr * 16 + t;
            const int hsh = ((t >> 2) & 3) << 3;

            float sv[8];
            #pragma unroll
            for (int j = 0; j < 8; j++) sv[j] = sS[t * SUB + ((lane + 64 * j) ^ hsh)];

            float m = sv[0];
            #pragma unroll
            for (int j = 1; j < 8; j++) m = fmaxf(m, sv[j]);
            #pragma unroll
            for (int off = 32; off > 0; off >>= 1) m = fmaxf(m, __shfl_xor(m, off));

            auto wave_cnt = [&](float tau) -> int {
                int c = 0;
                #pragma unroll
                for (int j = 0; j < 8; j++)
                    c += __popcll(__ballot(sv[j] > tau));
                return c;
            };

            float lo = m - 0.5f, hi = m;
            while (wave_cnt(lo) < 9) lo -= 0.5f;
            for (int it = 0; it < 14; it++) {
                float mid = 0.5f * (lo + hi);
                if (wave_cnt(mid) >= 9) lo = mid; else hi = mid;
            }
            int ch8 = wave_cnt(hi);

            float v8 = 1e30f, v9 = -1e30f;
            #pragma unroll
            for (int j = 0; j < 8; j++) {
                bool sel = sv[j] > hi;
                v8 = sel ? fminf(v8, sv[j]) : v8;
                v9 = sel ? v9 : fmaxf(v9, sv[j]);
            }
            #pragma unroll
            for (int off = 32; off > 0; off >>= 1) {
                v8 = fminf(v8, __shfl_xor(v8, off));
                v9 = fmaxf(v9, __shfl_xor(v9, off));
            }

            if (ch8 == 8 && (v8 - v9) > 1e-3f) {
                // fast path: coarse top-8 set exact at ~5-sigma margin
                int base = 0;
                #pragma unroll
                for (int j = 0; j < 8; j++) {
                    unsigned long long mk = __ballot(sv[j] > hi);
                    if (sv[j] > hi) {
                        int pos = base + __popcll(mk & ((1ULL << lane) - 1ULL));
                        tk_idx[((size_t)tok * 2 + hf) * TOPK + pos] = lane + 64 * j;
                        tk_val[((size_t)tok * 2 + hf) * TOPK + pos] = sv[j];
                    }
                    base += __popcll(mk);
                }
            } else {
                // slow path (~4%): coarse top-16 + fp64 rescore, exact order
                int cand[NCAND];
                #pragma unroll
                for (int r = 0; r < NCAND; r++) {
                    float bv = sv[0]; int bj = 0;
                    #pragma unroll
                    for (int j = 1; j < 8; j++) if (sv[j] > bv) { bv = sv[j]; bj = j; }
                    int bidx = lane + 64 * bj;
                    #pragma unroll
                    for (int off = 32; off > 0; off >>= 1) {
                        float ov = __shfl_xor(bv, off);
                        int   oi = __shfl_xor(bidx, off);
                        if (ov > bv || (ov == bv && oi < bidx)) { bv = ov; bidx = oi; }
                    }
                    cand[r] = bidx;
                    int jj = bidx >> 6;
                    if ((bidx & 63) == lane) {
                        #pragma unroll
                        for (int j = 0; j < 8; j++) if (j == jj) sv[j] = -INFINITY;
                    }
                }
                double qd[8];
                #pragma unroll
                for (int j = 0; j < 8; j++)
                    qd[j] = (double)query[(size_t)tok * DDIM + qoff + lane + 64 * j];
                double rv[NCAND];
                #pragma unroll
                for (int r = 0; r < NCAND; r++) {
                    const float* __restrict__ crow = &cbf[(size_t)cand[r] * KDIM];
                    double a = 0.0;
                    #pragma unroll
                    for (int j = 0; j < 8; j++)
                        a = fma(qd[j], (double)crow[lane + 64 * j], a);
                    #pragma unroll
                    for (int off = 32; off > 0; off >>= 1)
                        a += __shfl_xor(a, off);
                    rv[r] = a;
                }
                if (lane == 0) {
                    #pragma unroll
                    for (int r = 0; r < NCAND; r++) {
                        int rk = 0;
                        #pragma unroll
                        for (int mm = 0; mm < NCAND; mm++)
                            if (rv[mm] > rv[r] || (rv[mm] == rv[r] && cand[mm] < cand[r])) rk++;
                        if (rk < TOPK) {
                            tk_idx[((size_t)tok * 2 + hf) * TOPK + rk] = cand[r];
                            tk_val[((size_t)tok * 2 + hf) * TOPK + rk] = (float)rv[r];
                        }
                    }
                }
            }
        }
    };

    // ---- round 0: dump acc0 inline (all indices static) ----
    #pragma unroll
    for (int nt = 0; nt < 8; nt++)
        #pragma unroll
        for (int r = 0; r < 4; r++) {
            int t = lh * 4 + r;
            int c = wid * 128 + nt * 16 + l15;
            sS[t * SUB + (c ^ (lh << 3))] = acc0[nt][r];
        }
    __syncthreads();
    topk16(0);
    __syncthreads();

    // ---- round 1: dump acc1 inline ----
    #pragma unroll
    for (int nt = 0; nt < 8; nt++)
        #pragma unroll
        for (int r = 0; r < 4; r++) {
            int t = lh * 4 + r;
            int c = wid * 128 + nt * 16 + l15;
            sS[t * SUB + (c ^ (lh << 3))] = acc1[nt][r];
        }
    __syncthreads();
    topk16(1);
}

// ---------------------------------------------------------------------------
// Kernel 2: one wave per token. float4 loads, 2 value rows per instruction
// (lanes 0-31 even j, lanes 32-63 odd j), shfl_xor(32) combine.
// 32 TA-instructions per token instead of 64.
// ---------------------------------------------------------------------------
__global__ __launch_bounds__(256)
void gather_kernel(const float* __restrict__ values,
                   const int*   __restrict__ tk_idx,
                   const float* __restrict__ tk_val,
                   float* __restrict__ out)
{
    const int tid  = threadIdx.x;
    const int lane = tid & 63;
    const int tok  = blockIdx.x * 4 + (tid >> 6);

    const int b1 = (tok * 2 + 0) * TOPK;
    const int b2 = (tok * 2 + 1) * TOPK;

    float v1[8], v2[8]; int i1[8], i2[8];
    #pragma unroll
    for (int j = 0; j < 8; j++) {
        i1[j] = tk_idx[b1 + j]; v1[j] = tk_val[b1 + j];
        i2[j] = tk_idx[b2 + j]; v2[j] = tk_val[b2 + j];
    }

    float m1 = v1[0], m2 = v2[0];
    #pragma unroll
    for (int j = 1; j < 8; j++) { m1 = fmaxf(m1, v1[j]); m2 = fmaxf(m2, v2[j]); }

    float w1[8], w2[8], s1 = 0.f, s2 = 0.f;
    #pragma unroll
    for (int j = 0; j < 8; j++) {
        w1[j] = expf(v1[j] - m1); s1 += w1[j];
        w2[j] = expf(v2[j] - m2); s2 += w2[j];
    }
    const float inv1 = 1.f / s1, inv2 = 1.f / s2;
    #pragma unroll
    for (int j = 0; j < 8; j++) { w1[j] *= inv1; w2[j] *= inv2; }

    const int hi  = lane >> 5;          // 0: even j, 1: odd j
    const int col = lane & 31;          // float4 column within row
    const float4* vbase = (const float4*)values;

    float4 a0 = {0.f, 0.f, 0.f, 0.f}, a1 = {0.f, 0.f, 0.f, 0.f};
    #pragma unroll
    for (int p = 0; p < 32; p += 2) {
        const int ia = p >> 2,       ja = ((p & 3) << 1) | hi;
        const int ib = (p + 1) >> 2, jb = (((p + 1) & 3) << 1) | hi;
        float4 ra = vbase[(size_t)(i1[ia] * SUB + i2[ja]) * 32 + col];
        float4 rb = vbase[(size_t)(i1[ib] * SUB + i2[jb]) * 32 + col];
        const float wa = w1[ia] * w2[ja];
        const float wb = w1[ib] * w2[jb];
        a0.x = fmaf(wa, ra.x, a0.x); a0.y = fmaf(wa, ra.y, a0.y);
        a0.z = fmaf(wa, ra.z, a0.z); a0.w = fmaf(wa, ra.w, a0.w);
        a1.x = fmaf(wb, rb.x, a1.x); a1.y = fmaf(wb, rb.y, a1.y);
        a1.z = fmaf(wb, rb.z, a1.z); a1.w = fmaf(wb, rb.w, a1.w);
    }
    float4 s;
    s.x = a0.x + a1.x; s.y = a0.y + a1.y; s.z = a0.z + a1.z; s.w = a0.w + a1.w;
    s.x += __shfl_xor(s.x, 32);
    s.y += __shfl_xor(s.y, 32);
    s.z += __shfl_xor(s.z, 32);
    s.w += __shfl_xor(s.w, 32);
    if (hi == 0)
        *(float4*)(out + (size_t)tok * VDIM + col * 4) = s;
}

extern "C" void kernel_launch(void* const* d_in, const int* in_sizes, int n_in,
                              void* d_out, int out_size, void* d_ws, size_t ws_size,
                              hipStream_t stream) {
    const float* query  = (const float*)d_in[0];
    const float* cb1    = (const float*)d_in[1];
    const float* cb2    = (const float*)d_in[2];
    const float* values = (const float*)d_in[3];
    float* out = (float*)d_out;

    char* ws = (char*)d_ws;
    int*   tk_idx = (int*)ws;                    // 1 MB
    float* tk_val = (float*)(ws + (1u << 20));   // 1 MB
    char*  Bp     = ws + (2u << 20);             // 1 MB f16 B fragments

    cvt_bfrag<<<256, 256, 0, stream>>>(cb1, cb2, Bp);
    dim3 g1(NTOK / TMB, 2);
    score_topk_fused<<<g1, 256, 0, stream>>>(query, cb1, cb2, Bp, tk_idx, tk_val);
    gather_kernel<<<NTOK / 4, 256, 0, stream>>>(values, tk_idx, tk_val, out);
}